// Round 4
// baseline (247.092 us; speedup 1.0000x reference)
//
#include <hip/hip_runtime.h>
#include <hip/hip_fp16.h>

// GCN encoder: out = A' relu(A' (x W1) + b1) W2 + b2, A' = D^-1/2 (A+I) D^-1/2
// Round 11: R9/R10's global-atomic padded scatter FAILED post-timing (lost-edge
// scale divergence 6.5e-2, nondeterministic across graph replays) and was 2x
// slower (3.2M contended global atomics). Revert to R8's proven deterministic
// two-level-scan CSR build (227us, passed) and keep only the SAFE fusions:
// (a) g1 stores f16(h) UNSCALED -> gemm1 depends only on inputs -> fused with
//     k_count (block-range split fat kernel); agg1 gathers dinv[src] per edge
//     (same index as g1 gather, 400KB L2-resident table).
// (b) agg2+gemm2 fused: aggregate 32 nodes into LDS [16][32] tile then the
//     register-blocked gemm (kills 12.8MB p2f round-trip + 1 launch).
// 9 -> 7 dispatches; zero global atomics; CSR is exact (no holes, no drops).
// Algebra: p[d] = dinv_d*(dinv_d*h_d + sum_s dinv_s*h_s).

#define NN 100000
#define NE 1600000
#define FI 128
#define FH 16
#define CB 64                  // nodes per bucket
#define NB 1563                // ceil(NN/64); NB*64 = 100032
#define GC 512                 // edge chunks
#define CHUNK 3125             // NE/GC exactly
#define SCB 16                 // buckets per scan block

__device__ __forceinline__ float fc(const float4& v, int i) {
    return i == 0 ? v.x : i == 1 ? v.y : i == 2 ? v.z : v.w;
}

// ---------- fat kernel: count (blocks [0,GC)) + gemm1 (blocks [GC, GC+391)) ----------
// hist layout: hist[c * NB + b]  (chunk-major -> coalesced in count/scatter)
// gemm1: g1 = f16(x @ W1), no dinv scale (deferred to consumers).
__global__ __launch_bounds__(256) void k_count_gemm1(const int* __restrict__ dst,
                                                     int* __restrict__ hist,
                                                     const float* __restrict__ x,
                                                     const float* __restrict__ W1,
                                                     __half2* __restrict__ g1) {
    __shared__ int h[NB];
    __shared__ __align__(16) float w[FI * FH];
    if (blockIdx.x < GC) {
        // ---- count ----
        for (int i = threadIdx.x; i < NB; i += 256) h[i] = 0;
        __syncthreads();
        int base = blockIdx.x * CHUNK;
        for (int i = base + threadIdx.x; i < base + CHUNK; i += 256)
            atomicAdd(&h[dst[i] >> 6], 1);
        __syncthreads();
        for (int b = threadIdx.x; b < NB; b += 256)
            hist[blockIdx.x * NB + b] = h[b];
    } else {
        // ---- gemm1: 256 nodes/block, thread = 4 nodes x 4 feats ----
        float4* w4s = (float4*)w;
        w4s[threadIdx.x] = ((const float4*)W1)[threadIdx.x];
        w4s[threadIdx.x + 256] = ((const float4*)W1)[threadIdx.x + 256];
        __syncthreads();
        int fg = threadIdx.x & 3;          // feature quad
        int ng = threadIdx.x >> 2;         // node group
        int r0 = (blockIdx.x - GC) * 256 + ng * 4;
        const float4* x4 = (const float4*)x;
        int rr[4]; bool val[4];
        #pragma unroll
        for (int i = 0; i < 4; ++i) {
            val[i] = (r0 + i < NN);
            rr[i] = val[i] ? r0 + i : NN - 1;
        }
        float acc[4][4];
        #pragma unroll
        for (int i = 0; i < 4; ++i)
            #pragma unroll
            for (int j = 0; j < 4; ++j) acc[i][j] = 0.f;
        #pragma unroll 2
        for (int k4 = 0; k4 < 32; ++k4) {
            float4 xv[4];
            #pragma unroll
            for (int i = 0; i < 4; ++i) xv[i] = x4[rr[i] * 32 + k4];
            #pragma unroll
            for (int kk = 0; kk < 4; ++kk) {
                float4 wv = w4s[(k4 * 4 + kk) * 4 + fg];
                #pragma unroll
                for (int i = 0; i < 4; ++i) {
                    float xk = fc(xv[i], kk);
                    acc[i][0] += xk * wv.x; acc[i][1] += xk * wv.y;
                    acc[i][2] += xk * wv.z; acc[i][3] += xk * wv.w;
                }
            }
        }
        #pragma unroll
        for (int i = 0; i < 4; ++i) if (val[i]) {
            g1[rr[i] * 8 + fg * 2]     = __floats2half2_rn(acc[i][0], acc[i][1]);
            g1[rr[i] * 8 + fg * 2 + 1] = __floats2half2_rn(acc[i][2], acc[i][3]);
        }
    }
}

// per-bucket exclusive scan over chunks; 16 buckets/block, coalesced loads.
__global__ __launch_bounds__(256) void k_scan_chunks(int* __restrict__ hist,
                                                     int* __restrict__ totals) {
    __shared__ int s[GC * SCB];                       // 32 KB
    int b0 = blockIdx.x * SCB;
    int o[GC * SCB / 256];
    #pragma unroll
    for (int r = 0; r < GC * SCB / 256; ++r) {
        int idx = r * 256 + threadIdx.x;
        int c = idx >> 4, bl = idx & (SCB - 1), b = b0 + bl;
        int v = (b < NB) ? hist[c * NB + b] : 0;
        s[idx] = v;
        o[r] = v;
    }
    __syncthreads();
    for (int off = 1; off < GC; off <<= 1) {
        int t[GC * SCB / 256];
        #pragma unroll
        for (int r = 0; r < GC * SCB / 256; ++r) {
            int idx = r * 256 + threadIdx.x;
            int c = idx >> 4;
            t[r] = (c >= off) ? s[idx - off * SCB] : 0;
        }
        __syncthreads();
        #pragma unroll
        for (int r = 0; r < GC * SCB / 256; ++r) {
            int idx = r * 256 + threadIdx.x;
            s[idx] += t[r];
        }
        __syncthreads();
    }
    #pragma unroll
    for (int r = 0; r < GC * SCB / 256; ++r) {
        int idx = r * 256 + threadIdx.x;
        int c = idx >> 4, bl = idx & (SCB - 1), b = b0 + bl;
        if (b < NB) {
            hist[c * NB + b] = s[idx] - o[r];          // exclusive within bucket
            if (c == GC - 1) totals[b] = s[idx];       // bucket total
        }
    }
}

__global__ __launch_bounds__(1024) void k_scan_buckets(const int* __restrict__ totals,
                                                       int* __restrict__ bucketStart,
                                                       int* __restrict__ rowStart) {
    __shared__ int s[1024];
    int tid = threadIdx.x;
    int i0 = 2 * tid, i1 = i0 + 1;
    int a = (i0 < NB) ? totals[i0] : 0;
    int b = (i1 < NB) ? totals[i1] : 0;
    s[tid] = a + b;
    __syncthreads();
    #pragma unroll
    for (int off = 1; off < 1024; off <<= 1) {
        int t = (tid >= off) ? s[tid - off] : 0;
        __syncthreads();
        s[tid] += t;
        __syncthreads();
    }
    int excl = s[tid] - (a + b);
    if (i0 < NB) bucketStart[i0] = excl;
    if (i1 < NB) bucketStart[i1] = excl + a;
    if (tid == 0) { bucketStart[NB] = NE; rowStart[NN] = NE; }
}

__global__ __launch_bounds__(256) void k_scatter(const int* __restrict__ src,
                                                 const int* __restrict__ dst,
                                                 const int* __restrict__ hist,
                                                 const int* __restrict__ bucketStart,
                                                 int* __restrict__ packed) {
    __shared__ int cur[NB];
    for (int b = threadIdx.x; b < NB; b += 256)
        cur[b] = hist[blockIdx.x * NB + b] + bucketStart[b];   // addback folded in
    __syncthreads();
    int base = blockIdx.x * CHUNK;
    for (int i = base + threadIdx.x; i < base + CHUNK; i += 256) {
        int d = dst[i];
        int pos = atomicAdd(&cur[d >> 6], 1);
        packed[pos] = src[i] | ((d & 63) << 17);   // src < 2^17, local node in [0,64)
    }
}

// per-bucket sort -> exact CSR + rowStart + dinv (int LDS atomics only)
__global__ __launch_bounds__(256) void k_bsort(const int* __restrict__ packed,
                                               const int* __restrict__ bucketStart,
                                               int* __restrict__ csr,
                                               int* __restrict__ rowStart,
                                               float* __restrict__ dinv) {
    __shared__ int cnt[CB];
    __shared__ int rs[CB];
    __shared__ int cur[CB];
    if (threadIdx.x < CB) cnt[threadIdx.x] = 0;
    __syncthreads();
    int s0 = bucketStart[blockIdx.x], s1 = bucketStart[blockIdx.x + 1];
    for (int i = s0 + threadIdx.x; i < s1; i += 256)
        atomicAdd(&cnt[(packed[i] >> 17) & 63], 1);
    __syncthreads();
    if (threadIdx.x < CB) rs[threadIdx.x] = cnt[threadIdx.x];
    __syncthreads();
    #pragma unroll
    for (int off = 1; off < CB; off <<= 1) {
        int t = 0;
        if (threadIdx.x < CB && threadIdx.x >= off) t = rs[threadIdx.x - off];
        __syncthreads();
        if (threadIdx.x < CB) rs[threadIdx.x] += t;
        __syncthreads();
    }
    if (threadIdx.x < CB) {
        int start = s0 + rs[threadIdx.x] - cnt[threadIdx.x];   // exclusive
        cur[threadIdx.x] = start;
        int node = blockIdx.x * CB + threadIdx.x;
        if (node < NN) {
            rowStart[node] = start;
            dinv[node] = rsqrtf((float)(cnt[threadIdx.x] + 1));
        }
    }
    __syncthreads();
    for (int i = s0 + threadIdx.x; i < s1; i += 256) {
        int pk = packed[i];
        int pos = atomicAdd(&cur[(pk >> 17) & 63], 1);
        csr[pos] = pk & 131071;
    }
}

// agg layer 1: 8 threads/node, f32 register accumulation, zero atomics.
// g1 holds UNSCALED h; gather dinv[src] per edge.
// g2 = f16(relu(dv*acc + b1) * dv), acc = dv*h_d + sum_s dinv_s*h_s
__global__ __launch_bounds__(256) void k_agg1(const int* __restrict__ csr,
                                              const int* __restrict__ rowStart,
                                              const __half2* __restrict__ g1,
                                              const float* __restrict__ dinv,
                                              const float* __restrict__ b1,
                                              __half2* __restrict__ g2) {
    int gid = blockIdx.x * 256 + threadIdx.x;
    int node = gid >> 3, c = gid & 7;
    if (node >= NN) return;
    int s0 = rowStart[node], s1 = rowStart[node + 1];
    float dv = dinv[node];
    float2 fs = __half22float2(g1[node * 8 + c]);
    float2 acc = make_float2(dv * fs.x, dv * fs.y);   // self-loop term dinv_d*h_d
    int e = s0;
    for (; e + 3 < s1; e += 4) {
        int i0 = csr[e], i1 = csr[e + 1], i2 = csr[e + 2], i3 = csr[e + 3];
        float d0 = dinv[i0], d1 = dinv[i1], d2 = dinv[i2], d3 = dinv[i3];
        float2 f0 = __half22float2(g1[i0 * 8 + c]);
        float2 f1 = __half22float2(g1[i1 * 8 + c]);
        float2 f2 = __half22float2(g1[i2 * 8 + c]);
        float2 f3 = __half22float2(g1[i3 * 8 + c]);
        acc.x = fmaf(d0, f0.x, fmaf(d1, f1.x, fmaf(d2, f2.x, fmaf(d3, f3.x, acc.x))));
        acc.y = fmaf(d0, f0.y, fmaf(d1, f1.y, fmaf(d2, f2.y, fmaf(d3, f3.y, acc.y))));
    }
    for (; e < s1; ++e) {
        int i0 = csr[e];
        float d0 = dinv[i0];
        float2 f = __half22float2(g1[i0 * 8 + c]);
        acc.x = fmaf(d0, f.x, acc.x);
        acc.y = fmaf(d0, f.y, acc.y);
    }
    float2 bb = *(const float2*)(b1 + 2 * c);
    float vx = fmaxf(dv * acc.x + bb.x, 0.f) * dv;
    float vy = fmaxf(dv * acc.y + bb.y, 0.f) * dv;
    g2[node * 8 + c] = __floats2half2_rn(vx, vy);
}

// agg layer 2 fused with gemm2: block = 32 nodes.
// g2 is pre-scaled by dinv of its node, so plain sum + dv multiply.
// Phase A: p2 = dv*(g2_d + sum) into LDS pst[16][32] (8 threads/node, f32 regs).
// Phase B: out = pst^T @ W2 + b2 (register-blocked, 4n x 4f per thread).
__global__ __launch_bounds__(256) void k_aggemm2(const int* __restrict__ csr,
                                                 const int* __restrict__ rowStart,
                                                 const float* __restrict__ dinv,
                                                 const __half2* __restrict__ g2,
                                                 const float* __restrict__ W2,
                                                 const float* __restrict__ b2,
                                                 float* __restrict__ out) {
    __shared__ __align__(16) float w[FH * FI];
    __shared__ __align__(16) float pst[FH][32];
    float4* w4s = (float4*)w;
    w4s[threadIdx.x] = ((const float4*)W2)[threadIdx.x];
    w4s[threadIdx.x + 256] = ((const float4*)W2)[threadIdx.x + 256];
    int base = blockIdx.x * 32;
    int ln = threadIdx.x >> 3, c = threadIdx.x & 7;
    int node = base + ln;
    float2 acc = make_float2(0.f, 0.f);
    if (node < NN) {
        int s0 = rowStart[node], s1 = rowStart[node + 1];
        acc = __half22float2(g2[node * 8 + c]);      // self-loop term
        int e = s0;
        for (; e + 3 < s1; e += 4) {
            int i0 = csr[e], i1 = csr[e + 1], i2 = csr[e + 2], i3 = csr[e + 3];
            float2 f0 = __half22float2(g2[i0 * 8 + c]);
            float2 f1 = __half22float2(g2[i1 * 8 + c]);
            float2 f2 = __half22float2(g2[i2 * 8 + c]);
            float2 f3 = __half22float2(g2[i3 * 8 + c]);
            acc.x += (f0.x + f1.x) + (f2.x + f3.x);
            acc.y += (f0.y + f1.y) + (f2.y + f3.y);
        }
        for (; e < s1; ++e) {
            float2 f = __half22float2(g2[csr[e] * 8 + c]);
            acc.x += f.x; acc.y += f.y;
        }
        float dv = dinv[node];
        acc.x *= dv; acc.y *= dv;
    }
    pst[2 * c][ln]     = acc.x;
    pst[2 * c + 1][ln] = acc.y;
    __syncthreads();
    // ---- gemm2 ----
    int fg = threadIdx.x & 31;    // feature quad
    int ng = threadIdx.x >> 5;    // node group
    float4 bb = ((const float4*)b2)[fg];
    float a2[4][4];
    #pragma unroll
    for (int i = 0; i < 4; ++i) {
        a2[i][0] = bb.x; a2[i][1] = bb.y; a2[i][2] = bb.z; a2[i][3] = bb.w;
    }
    #pragma unroll
    for (int k = 0; k < FH; ++k) {
        float4 xk = *(float4*)&pst[k][ng * 4];
        float4 wv = w4s[k * 32 + fg];
        #pragma unroll
        for (int i = 0; i < 4; ++i) {
            float xv = fc(xk, i);
            a2[i][0] += xv * wv.x; a2[i][1] += xv * wv.y;
            a2[i][2] += xv * wv.z; a2[i][3] += xv * wv.w;
        }
    }
    #pragma unroll
    for (int i = 0; i < 4; ++i) {
        int gn = base + ng * 4 + i;
        if (gn < NN)
            ((float4*)out)[gn * 32 + fg] =
                make_float4(a2[i][0], a2[i][1], a2[i][2], a2[i][3]);
    }
}

extern "C" void kernel_launch(void* const* d_in, const int* in_sizes, int n_in,
                              void* d_out, int out_size, void* d_ws, size_t ws_size,
                              hipStream_t stream) {
    const float* x  = (const float*)d_in[0];
    const int*   ei = (const int*)d_in[1];
    const float* W1 = (const float*)d_in[2];
    const float* b1 = (const float*)d_in[3];
    const float* W2 = (const float*)d_in[4];
    const float* b2 = (const float*)d_in[5];
    float* out = (float*)d_out;

    const int* src = ei;
    const int* dst = ei + NE;

    // workspace layout (~20.0 MB, 4-B units)
    int*   totals      = (int*)d_ws;                  // [NB]
    int*   bucketStart = totals + NB;                 // [NB+1]
    int*   rowStart    = bucketStart + NB + 1;        // [NN+1]
    float* dinv        = (float*)(rowStart + NN + 1); // [NN]
    int*   csr         = (int*)(dinv + NN);           // [NE]
    int*   hist        = csr;                         // [GC*NB]=800256 <= NE, dead before k_bsort
    int*   packed      = csr + NE;                    // [NE]
    __half2* g1        = (__half2*)(packed + NE);     // [NN*8] own region (written before packed consumed)
    __half2* g2        = g1 + NN * 8;                 // [NN*8]

    k_count_gemm1 <<<GC + (NN + 255) / 256, 256, 0, stream>>>(dst, hist, x, W1, g1);
    k_scan_chunks <<<(NB + SCB - 1) / SCB, 256, 0, stream>>>(hist, totals);
    k_scan_buckets<<<1, 1024, 0, stream>>>(totals, bucketStart, rowStart);
    k_scatter     <<<GC, 256, 0, stream>>>(src, dst, hist, bucketStart, packed);
    k_bsort       <<<NB, 256, 0, stream>>>(packed, bucketStart, csr, rowStart, dinv);
    k_agg1        <<<(NN * 8) / 256, 256, 0, stream>>>(csr, rowStart, g1, dinv, b1, g2);
    k_aggemm2     <<<(NN + 31) / 32, 256, 0, stream>>>(csr, rowStart, dinv, g2, W2, b2, out);
}

// Round 5
// 245.277 us; speedup vs baseline: 1.0074x; 1.0074x over previous
//
#include <hip/hip_runtime.h>
#include <hip/hip_fp16.h>

// GCN encoder: out = A' relu(A' (x W1) + b1) W2 + b2, A' = D^-1/2 (A+I) D^-1/2
// Round 12: R11 fixes. agg1's per-edge dinv[src] gather (R11a) was the regression
// (doubled dependent loads); aggemm2's 44us is gather-latency, not bank conflicts
// (350K decoded = pst stride-64 8-way write conflict, only ~0.3us).
// (a) bsort scales g1 in-place for its own 64 contiguous nodes (2KB coalesced span,
//     ~1us) -> agg1 reverts to R8's pre-scaled algebra, zero per-edge dinv loads,
//     while gemm1 stays fused with count (no bsort dependency).
// (b) both agg loops: 4 threads/node, 8B h2x2 gathers -> half the load instrs,
//     2 independent f32x2 accumulator chains per thread (2x MLP).
// (c) aggemm2: 64-node blocks (bucket-aligned), pst stride 68 (2-way max = free),
//     Phase B = 8 nodes x 4 feats per thread.
// (d) count_gemm1: h[] unioned into w[] (-6.2KB LDS).
// Algebra: g1 = f16(f16(h)*dinv); p[d] = dinv_d*(g1_d + sum_s g1_s).

#define NN 100000
#define NE 1600000
#define FI 128
#define FH 16
#define CB 64                  // nodes per bucket
#define NB 1563                // ceil(NN/64); NB*64 = 100032
#define GC 512                 // edge chunks
#define CHUNK 3125             // NE/GC exactly
#define SCB 16                 // buckets per scan block

__device__ __forceinline__ float fc(const float4& v, int i) {
    return i == 0 ? v.x : i == 1 ? v.y : i == 2 ? v.z : v.w;
}

struct h2x2 { __half2 a, b; };   // 8B: two half2 = 4 features

// ---------- fat kernel: count (blocks [0,GC)) + gemm1 (blocks [GC, GC+391)) ----------
// hist layout: hist[c * NB + b]  (chunk-major -> coalesced in count/scatter)
// gemm1: g1 = f16(x @ W1), unscaled (bsort applies dinv in-place later).
__global__ __launch_bounds__(256) void k_count_gemm1(const int* __restrict__ dst,
                                                     int* __restrict__ hist,
                                                     const float* __restrict__ x,
                                                     const float* __restrict__ W1,
                                                     __half2* __restrict__ g1) {
    __shared__ __align__(16) float w[FI * FH];        // 8KB; count half reuses as int h[NB]
    if (blockIdx.x < GC) {
        // ---- count ----
        int* h = (int*)w;                              // NB ints = 6252B <= 8192B
        for (int i = threadIdx.x; i < NB; i += 256) h[i] = 0;
        __syncthreads();
        int base = blockIdx.x * CHUNK;
        for (int i = base + threadIdx.x; i < base + CHUNK; i += 256)
            atomicAdd(&h[dst[i] >> 6], 1);
        __syncthreads();
        for (int b = threadIdx.x; b < NB; b += 256)
            hist[blockIdx.x * NB + b] = h[b];
    } else {
        // ---- gemm1: 256 nodes/block, thread = 4 nodes x 4 feats ----
        float4* w4s = (float4*)w;
        w4s[threadIdx.x] = ((const float4*)W1)[threadIdx.x];
        w4s[threadIdx.x + 256] = ((const float4*)W1)[threadIdx.x + 256];
        __syncthreads();
        int fg = threadIdx.x & 3;          // feature quad
        int ng = threadIdx.x >> 2;         // node group
        int r0 = (blockIdx.x - GC) * 256 + ng * 4;
        const float4* x4 = (const float4*)x;
        int rr[4]; bool val[4];
        #pragma unroll
        for (int i = 0; i < 4; ++i) {
            val[i] = (r0 + i < NN);
            rr[i] = val[i] ? r0 + i : NN - 1;
        }
        float acc[4][4];
        #pragma unroll
        for (int i = 0; i < 4; ++i)
            #pragma unroll
            for (int j = 0; j < 4; ++j) acc[i][j] = 0.f;
        #pragma unroll 2
        for (int k4 = 0; k4 < 32; ++k4) {
            float4 xv[4];
            #pragma unroll
            for (int i = 0; i < 4; ++i) xv[i] = x4[rr[i] * 32 + k4];
            #pragma unroll
            for (int kk = 0; kk < 4; ++kk) {
                float4 wv = w4s[(k4 * 4 + kk) * 4 + fg];
                #pragma unroll
                for (int i = 0; i < 4; ++i) {
                    float xk = fc(xv[i], kk);
                    acc[i][0] += xk * wv.x; acc[i][1] += xk * wv.y;
                    acc[i][2] += xk * wv.z; acc[i][3] += xk * wv.w;
                }
            }
        }
        #pragma unroll
        for (int i = 0; i < 4; ++i) if (val[i]) {
            g1[rr[i] * 8 + fg * 2]     = __floats2half2_rn(acc[i][0], acc[i][1]);
            g1[rr[i] * 8 + fg * 2 + 1] = __floats2half2_rn(acc[i][2], acc[i][3]);
        }
    }
}

// per-bucket exclusive scan over chunks; 16 buckets/block, coalesced loads.
__global__ __launch_bounds__(256) void k_scan_chunks(int* __restrict__ hist,
                                                     int* __restrict__ totals) {
    __shared__ int s[GC * SCB];                       // 32 KB
    int b0 = blockIdx.x * SCB;
    int o[GC * SCB / 256];
    #pragma unroll
    for (int r = 0; r < GC * SCB / 256; ++r) {
        int idx = r * 256 + threadIdx.x;
        int c = idx >> 4, bl = idx & (SCB - 1), b = b0 + bl;
        int v = (b < NB) ? hist[c * NB + b] : 0;
        s[idx] = v;
        o[r] = v;
    }
    __syncthreads();
    for (int off = 1; off < GC; off <<= 1) {
        int t[GC * SCB / 256];
        #pragma unroll
        for (int r = 0; r < GC * SCB / 256; ++r) {
            int idx = r * 256 + threadIdx.x;
            int c = idx >> 4;
            t[r] = (c >= off) ? s[idx - off * SCB] : 0;
        }
        __syncthreads();
        #pragma unroll
        for (int r = 0; r < GC * SCB / 256; ++r) {
            int idx = r * 256 + threadIdx.x;
            s[idx] += t[r];
        }
        __syncthreads();
    }
    #pragma unroll
    for (int r = 0; r < GC * SCB / 256; ++r) {
        int idx = r * 256 + threadIdx.x;
        int c = idx >> 4, bl = idx & (SCB - 1), b = b0 + bl;
        if (b < NB) {
            hist[c * NB + b] = s[idx] - o[r];          // exclusive within bucket
            if (c == GC - 1) totals[b] = s[idx];       // bucket total
        }
    }
}

__global__ __launch_bounds__(1024) void k_scan_buckets(const int* __restrict__ totals,
                                                       int* __restrict__ bucketStart,
                                                       int* __restrict__ rowStart) {
    __shared__ int s[1024];
    int tid = threadIdx.x;
    int i0 = 2 * tid, i1 = i0 + 1;
    int a = (i0 < NB) ? totals[i0] : 0;
    int b = (i1 < NB) ? totals[i1] : 0;
    s[tid] = a + b;
    __syncthreads();
    #pragma unroll
    for (int off = 1; off < 1024; off <<= 1) {
        int t = (tid >= off) ? s[tid - off] : 0;
        __syncthreads();
        s[tid] += t;
        __syncthreads();
    }
    int excl = s[tid] - (a + b);
    if (i0 < NB) bucketStart[i0] = excl;
    if (i1 < NB) bucketStart[i1] = excl + a;
    if (tid == 0) { bucketStart[NB] = NE; rowStart[NN] = NE; }
}

__global__ __launch_bounds__(256) void k_scatter(const int* __restrict__ src,
                                                 const int* __restrict__ dst,
                                                 const int* __restrict__ hist,
                                                 const int* __restrict__ bucketStart,
                                                 int* __restrict__ packed) {
    __shared__ int cur[NB];
    for (int b = threadIdx.x; b < NB; b += 256)
        cur[b] = hist[blockIdx.x * NB + b] + bucketStart[b];   // addback folded in
    __syncthreads();
    int base = blockIdx.x * CHUNK;
    for (int i = base + threadIdx.x; i < base + CHUNK; i += 256) {
        int d = dst[i];
        int pos = atomicAdd(&cur[d >> 6], 1);
        packed[pos] = src[i] | ((d & 63) << 17);   // src < 2^17, local node in [0,64)
    }
}

// per-bucket sort -> exact CSR + rowStart + dinv; then scale g1 rows of this
// bucket in-place by dinv (contiguous 2KB span, coalesced).
__global__ __launch_bounds__(256) void k_bsort(const int* __restrict__ packed,
                                               const int* __restrict__ bucketStart,
                                               int* __restrict__ csr,
                                               int* __restrict__ rowStart,
                                               float* __restrict__ dinv,
                                               __half2* __restrict__ g1) {
    __shared__ int cnt[CB];
    __shared__ int rs[CB];
    __shared__ int cur[CB];
    __shared__ float dvs[CB];
    if (threadIdx.x < CB) cnt[threadIdx.x] = 0;
    __syncthreads();
    int s0 = bucketStart[blockIdx.x], s1 = bucketStart[blockIdx.x + 1];
    for (int i = s0 + threadIdx.x; i < s1; i += 256)
        atomicAdd(&cnt[(packed[i] >> 17) & 63], 1);
    __syncthreads();
    if (threadIdx.x < CB) rs[threadIdx.x] = cnt[threadIdx.x];
    __syncthreads();
    #pragma unroll
    for (int off = 1; off < CB; off <<= 1) {
        int t = 0;
        if (threadIdx.x < CB && threadIdx.x >= off) t = rs[threadIdx.x - off];
        __syncthreads();
        if (threadIdx.x < CB) rs[threadIdx.x] += t;
        __syncthreads();
    }
    if (threadIdx.x < CB) {
        int start = s0 + rs[threadIdx.x] - cnt[threadIdx.x];   // exclusive
        cur[threadIdx.x] = start;
        float dv = rsqrtf((float)(cnt[threadIdx.x] + 1));
        dvs[threadIdx.x] = dv;
        int node = blockIdx.x * CB + threadIdx.x;
        if (node < NN) {
            rowStart[node] = start;
            dinv[node] = dv;
        }
    }
    __syncthreads();
    for (int i = s0 + threadIdx.x; i < s1; i += 256) {
        int pk = packed[i];
        int pos = atomicAdd(&cur[(pk >> 17) & 63], 1);
        csr[pos] = pk & 131071;
    }
    // ---- scale g1 rows of this bucket: half2 range [b*512, b*512+512) ----
    int gbase = blockIdx.x * (CB * 8);
    #pragma unroll
    for (int r = 0; r < 2; ++r) {
        int i = r * 256 + threadIdx.x;
        int gi = gbase + i;
        if (gi < NN * 8) {
            float dv = dvs[i >> 3];
            float2 f = __half22float2(g1[gi]);
            g1[gi] = __floats2half2_rn(f.x * dv, f.y * dv);
        }
    }
}

// agg layer 1: 4 threads/node, 8B h2x2 gathers, 2 independent f32x2 chains.
// g1 pre-scaled: g2 = f16(relu(dv*(g1_d + sum_s g1_s) + b1) * dv)
__global__ __launch_bounds__(256) void k_agg1(const int* __restrict__ csr,
                                              const int* __restrict__ rowStart,
                                              const __half2* __restrict__ g1,
                                              const float* __restrict__ dinv,
                                              const float* __restrict__ b1,
                                              __half2* __restrict__ g2) {
    int gid = blockIdx.x * 256 + threadIdx.x;
    int node = gid >> 2, c4 = gid & 3;
    if (node >= NN) return;
    int s0 = rowStart[node], s1 = rowStart[node + 1];
    h2x2 sv = *(const h2x2*)(g1 + node * 8 + 2 * c4);   // self-loop term
    float2 a0 = __half22float2(sv.a);
    float2 a1 = __half22float2(sv.b);
    int e = s0;
    for (; e + 3 < s1; e += 4) {
        int i0 = csr[e], i1 = csr[e + 1], i2 = csr[e + 2], i3 = csr[e + 3];
        h2x2 v0 = *(const h2x2*)(g1 + i0 * 8 + 2 * c4);
        h2x2 v1 = *(const h2x2*)(g1 + i1 * 8 + 2 * c4);
        h2x2 v2 = *(const h2x2*)(g1 + i2 * 8 + 2 * c4);
        h2x2 v3 = *(const h2x2*)(g1 + i3 * 8 + 2 * c4);
        float2 f0 = __half22float2(v0.a), f1 = __half22float2(v1.a);
        float2 f2 = __half22float2(v2.a), f3 = __half22float2(v3.a);
        float2 h0 = __half22float2(v0.b), h1 = __half22float2(v1.b);
        float2 h2 = __half22float2(v2.b), h3 = __half22float2(v3.b);
        a0.x += (f0.x + f1.x) + (f2.x + f3.x);
        a0.y += (f0.y + f1.y) + (f2.y + f3.y);
        a1.x += (h0.x + h1.x) + (h2.x + h3.x);
        a1.y += (h0.y + h1.y) + (h2.y + h3.y);
    }
    for (; e < s1; ++e) {
        h2x2 v = *(const h2x2*)(g1 + csr[e] * 8 + 2 * c4);
        float2 f = __half22float2(v.a), h = __half22float2(v.b);
        a0.x += f.x; a0.y += f.y; a1.x += h.x; a1.y += h.y;
    }
    float dv = dinv[node];
    float4 bb = *(const float4*)(b1 + 4 * c4);
    h2x2 o;
    o.a = __floats2half2_rn(fmaxf(dv * a0.x + bb.x, 0.f) * dv,
                            fmaxf(dv * a0.y + bb.y, 0.f) * dv);
    o.b = __floats2half2_rn(fmaxf(dv * a1.x + bb.z, 0.f) * dv,
                            fmaxf(dv * a1.y + bb.w, 0.f) * dv);
    *(h2x2*)(g2 + node * 8 + 2 * c4) = o;
}

// agg layer 2 fused with gemm2: block = 64 nodes (bucket-aligned).
// Phase A: 4 threads/node, p2 = dv*(g2_d + sum) into pst[16][68] (stride-68: 2-way max).
// Phase B: out = pst^T @ W2 + b2; thread = 8 nodes x 4 feats.
__global__ __launch_bounds__(256) void k_aggemm2(const int* __restrict__ csr,
                                                 const int* __restrict__ rowStart,
                                                 const float* __restrict__ dinv,
                                                 const __half2* __restrict__ g2,
                                                 const float* __restrict__ W2,
                                                 const float* __restrict__ b2,
                                                 float* __restrict__ out) {
    __shared__ __align__(16) float w[FH * FI];        // 8KB
    __shared__ float pst[FH][68];                      // 4.25KB, padded stride
    float4* w4s = (float4*)w;
    w4s[threadIdx.x] = ((const float4*)W2)[threadIdx.x];
    w4s[threadIdx.x + 256] = ((const float4*)W2)[threadIdx.x + 256];
    int base = blockIdx.x * 64;
    int ln = threadIdx.x >> 2, c4 = threadIdx.x & 3;
    int node = base + ln;
    float2 a0 = make_float2(0.f, 0.f), a1 = make_float2(0.f, 0.f);
    if (node < NN) {
        int s0 = rowStart[node], s1 = rowStart[node + 1];
        h2x2 sv = *(const h2x2*)(g2 + node * 8 + 2 * c4);   // self-loop term
        a0 = __half22float2(sv.a);
        a1 = __half22float2(sv.b);
        int e = s0;
        for (; e + 3 < s1; e += 4) {
            int i0 = csr[e], i1 = csr[e + 1], i2 = csr[e + 2], i3 = csr[e + 3];
            h2x2 v0 = *(const h2x2*)(g2 + i0 * 8 + 2 * c4);
            h2x2 v1 = *(const h2x2*)(g2 + i1 * 8 + 2 * c4);
            h2x2 v2 = *(const h2x2*)(g2 + i2 * 8 + 2 * c4);
            h2x2 v3 = *(const h2x2*)(g2 + i3 * 8 + 2 * c4);
            float2 f0 = __half22float2(v0.a), f1 = __half22float2(v1.a);
            float2 f2 = __half22float2(v2.a), f3 = __half22float2(v3.a);
            float2 h0 = __half22float2(v0.b), h1 = __half22float2(v1.b);
            float2 h2 = __half22float2(v2.b), h3 = __half22float2(v3.b);
            a0.x += (f0.x + f1.x) + (f2.x + f3.x);
            a0.y += (f0.y + f1.y) + (f2.y + f3.y);
            a1.x += (h0.x + h1.x) + (h2.x + h3.x);
            a1.y += (h0.y + h1.y) + (h2.y + h3.y);
        }
        for (; e < s1; ++e) {
            h2x2 v = *(const h2x2*)(g2 + csr[e] * 8 + 2 * c4);
            float2 f = __half22float2(v.a), h = __half22float2(v.b);
            a0.x += f.x; a0.y += f.y; a1.x += h.x; a1.y += h.y;
        }
        float dv = dinv[node];
        a0.x *= dv; a0.y *= dv; a1.x *= dv; a1.y *= dv;
    }
    pst[4 * c4 + 0][ln] = a0.x;
    pst[4 * c4 + 1][ln] = a0.y;
    pst[4 * c4 + 2][ln] = a1.x;
    pst[4 * c4 + 3][ln] = a1.y;
    __syncthreads();
    // ---- gemm2: thread = 8 nodes x 4 feats ----
    int fg = threadIdx.x & 31;    // feature quad
    int ng = threadIdx.x >> 5;    // node octet: nodes ng*8..ng*8+7
    float4 bb = ((const float4*)b2)[fg];
    float a2[8][4];
    #pragma unroll
    for (int i = 0; i < 8; ++i) {
        a2[i][0] = bb.x; a2[i][1] = bb.y; a2[i][2] = bb.z; a2[i][3] = bb.w;
    }
    #pragma unroll
    for (int k = 0; k < FH; ++k) {
        float4 wv = w4s[k * 32 + fg];
        #pragma unroll
        for (int i = 0; i < 8; ++i) {
            float xv = pst[k][ng * 8 + i];
            a2[i][0] += xv * wv.x; a2[i][1] += xv * wv.y;
            a2[i][2] += xv * wv.z; a2[i][3] += xv * wv.w;
        }
    }
    #pragma unroll
    for (int i = 0; i < 8; ++i) {
        int gn = base + ng * 8 + i;
        if (gn < NN)
            ((float4*)out)[gn * 32 + fg] =
                make_float4(a2[i][0], a2[i][1], a2[i][2], a2[i][3]);
    }
}

extern "C" void kernel_launch(void* const* d_in, const int* in_sizes, int n_in,
                              void* d_out, int out_size, void* d_ws, size_t ws_size,
                              hipStream_t stream) {
    const float* x  = (const float*)d_in[0];
    const int*   ei = (const int*)d_in[1];
    const float* W1 = (const float*)d_in[2];
    const float* b1 = (const float*)d_in[3];
    const float* W2 = (const float*)d_in[4];
    const float* b2 = (const float*)d_in[5];
    float* out = (float*)d_out;

    const int* src = ei;
    const int* dst = ei + NE;

    // workspace layout (~20.0 MB, 4-B units)
    int*   totals      = (int*)d_ws;                  // [NB]
    int*   bucketStart = totals + NB;                 // [NB+1]
    int*   rowStart    = bucketStart + NB + 1;        // [NN+1]
    float* dinv        = (float*)(rowStart + NN + 1); // [NN]
    int*   csr         = (int*)(dinv + NN);           // [NE]
    int*   hist        = csr;                         // [GC*NB]=800256 <= NE, dead before k_bsort
    int*   packed      = csr + NE;                    // [NE]
    __half2* g1        = (__half2*)(packed + NE);     // [NN*8] own region
    __half2* g2        = g1 + NN * 8;                 // [NN*8]

    k_count_gemm1 <<<GC + (NN + 255) / 256, 256, 0, stream>>>(dst, hist, x, W1, g1);
    k_scan_chunks <<<(NB + SCB - 1) / SCB, 256, 0, stream>>>(hist, totals);
    k_scan_buckets<<<1, 1024, 0, stream>>>(totals, bucketStart, rowStart);
    k_scatter     <<<GC, 256, 0, stream>>>(src, dst, hist, bucketStart, packed);
    k_bsort       <<<NB, 256, 0, stream>>>(packed, bucketStart, csr, rowStart, dinv, g1);
    k_agg1        <<<(NN * 4 + 255) / 256, 256, 0, stream>>>(csr, rowStart, g1, dinv, b1, g2);
    k_aggemm2     <<<(NN + 63) / 64, 256, 0, stream>>>(csr, rowStart, dinv, g2, W2, b2, out);
}

// Round 6
// 233.315 us; speedup vs baseline: 1.0590x; 1.0513x over previous
//
#include <hip/hip_runtime.h>
#include <hip/hip_fp16.h>

// GCN encoder: out = A' relu(A' (x W1) + b1) W2 + b2, A' = D^-1/2 (A+I) D^-1/2
// Round 13: R12 showed the aggs are CONCURRENCY-STARVED latency gathers (bank
// conflicts fixed 350K->50K yet slower; VGPR 76->108 cut occupancy 24.6->16.5%).
// Little's law: ~1.6M random L2 lines need ~27K in flight for ~10us; occupancy
// is the lever. So:
// (a) UNFUSE aggemm2 -> lean k_agg2 (8thr/node, ~32 VGPR, 8 waves/SIMD) +
//     standalone k_gemm2; p2 stored f16 (error +~2e-3, margin 9.1e-3).
// (b) padded CSR: bsort pads each node's list to mult-of-4 with sentinel NN
//     (zero row in g1/g2) -> branch-free int4+4-gather loop, no scalar tail.
//     rowSE=(start,paddedEnd); bucket regions +200 slots, 16B-aligned starts.
// (c) agg1 back to 8thr/node half2 gathers (beat R12's 4thr shape).
// Algebra: g1 = f16(f16(x@W1)*dinv); p[d] = dinv_d*(g1_d + sum_s g1_s).

#define NN 100000
#define NE 1600000
#define FI 128
#define FH 16
#define CB 64                  // nodes per bucket
#define NB 1563                // ceil(NN/64); NB*64 = 100032
#define GC 512                 // edge chunks
#define CHUNK 3125             // NE/GC exactly
#define SCB 16                 // buckets per scan block

__device__ __forceinline__ float fc(const float4& v, int i) {
    return i == 0 ? v.x : i == 1 ? v.y : i == 2 ? v.z : v.w;
}

// ---------- fat kernel: count (blocks [0,GC)) + gemm1 (blocks [GC, GC+391)) ----------
// hist layout: hist[c * NB + b]  (chunk-major -> coalesced in count/scatter)
// gemm1: g1 = f16(x @ W1), unscaled (bsort applies dinv in-place later).
__global__ __launch_bounds__(256) void k_count_gemm1(const int* __restrict__ dst,
                                                     int* __restrict__ hist,
                                                     const float* __restrict__ x,
                                                     const float* __restrict__ W1,
                                                     __half2* __restrict__ g1) {
    __shared__ __align__(16) float w[FI * FH];        // 8KB; count half reuses as int h[NB]
    if (blockIdx.x < GC) {
        int* h = (int*)w;                              // NB ints = 6252B <= 8192B
        for (int i = threadIdx.x; i < NB; i += 256) h[i] = 0;
        __syncthreads();
        int base = blockIdx.x * CHUNK;
        for (int i = base + threadIdx.x; i < base + CHUNK; i += 256)
            atomicAdd(&h[dst[i] >> 6], 1);
        __syncthreads();
        for (int b = threadIdx.x; b < NB; b += 256)
            hist[blockIdx.x * NB + b] = h[b];
    } else {
        // ---- gemm1: 256 nodes/block, thread = 4 nodes x 4 feats ----
        float4* w4s = (float4*)w;
        w4s[threadIdx.x] = ((const float4*)W1)[threadIdx.x];
        w4s[threadIdx.x + 256] = ((const float4*)W1)[threadIdx.x + 256];
        __syncthreads();
        int fg = threadIdx.x & 3;
        int ng = threadIdx.x >> 2;
        int r0 = (blockIdx.x - GC) * 256 + ng * 4;
        const float4* x4 = (const float4*)x;
        int rr[4]; bool val[4];
        #pragma unroll
        for (int i = 0; i < 4; ++i) {
            val[i] = (r0 + i < NN);
            rr[i] = val[i] ? r0 + i : NN - 1;
        }
        float acc[4][4];
        #pragma unroll
        for (int i = 0; i < 4; ++i)
            #pragma unroll
            for (int j = 0; j < 4; ++j) acc[i][j] = 0.f;
        #pragma unroll 2
        for (int k4 = 0; k4 < 32; ++k4) {
            float4 xv[4];
            #pragma unroll
            for (int i = 0; i < 4; ++i) xv[i] = x4[rr[i] * 32 + k4];
            #pragma unroll
            for (int kk = 0; kk < 4; ++kk) {
                float4 wv = w4s[(k4 * 4 + kk) * 4 + fg];
                #pragma unroll
                for (int i = 0; i < 4; ++i) {
                    float xk = fc(xv[i], kk);
                    acc[i][0] += xk * wv.x; acc[i][1] += xk * wv.y;
                    acc[i][2] += xk * wv.z; acc[i][3] += xk * wv.w;
                }
            }
        }
        #pragma unroll
        for (int i = 0; i < 4; ++i) if (val[i]) {
            g1[rr[i] * 8 + fg * 2]     = __floats2half2_rn(acc[i][0], acc[i][1]);
            g1[rr[i] * 8 + fg * 2 + 1] = __floats2half2_rn(acc[i][2], acc[i][3]);
        }
    }
}

// per-bucket exclusive scan over chunks; 16 buckets/block, coalesced loads.
__global__ __launch_bounds__(256) void k_scan_chunks(int* __restrict__ hist,
                                                     int* __restrict__ totals) {
    __shared__ int s[GC * SCB];                       // 32 KB
    int b0 = blockIdx.x * SCB;
    int o[GC * SCB / 256];
    #pragma unroll
    for (int r = 0; r < GC * SCB / 256; ++r) {
        int idx = r * 256 + threadIdx.x;
        int c = idx >> 4, bl = idx & (SCB - 1), b = b0 + bl;
        int v = (b < NB) ? hist[c * NB + b] : 0;
        s[idx] = v;
        o[r] = v;
    }
    __syncthreads();
    for (int off = 1; off < GC; off <<= 1) {
        int t[GC * SCB / 256];
        #pragma unroll
        for (int r = 0; r < GC * SCB / 256; ++r) {
            int idx = r * 256 + threadIdx.x;
            int c = idx >> 4;
            t[r] = (c >= off) ? s[idx - off * SCB] : 0;
        }
        __syncthreads();
        #pragma unroll
        for (int r = 0; r < GC * SCB / 256; ++r) {
            int idx = r * 256 + threadIdx.x;
            s[idx] += t[r];
        }
        __syncthreads();
    }
    #pragma unroll
    for (int r = 0; r < GC * SCB / 256; ++r) {
        int idx = r * 256 + threadIdx.x;
        int c = idx >> 4, bl = idx & (SCB - 1), b = b0 + bl;
        if (b < NB) {
            hist[c * NB + b] = s[idx] - o[r];          // exclusive within bucket
            if (c == GC - 1) totals[b] = s[idx];       // bucket total
        }
    }
}

// bucket scan + zero g1 sentinel row NN.
__global__ __launch_bounds__(1024) void k_scan_buckets(const int* __restrict__ totals,
                                                       int* __restrict__ bucketStart,
                                                       __half2* __restrict__ g1) {
    __shared__ int s[1024];
    int tid = threadIdx.x;
    if (tid < 8) g1[NN * 8 + tid] = __floats2half2_rn(0.f, 0.f);
    int i0 = 2 * tid, i1 = i0 + 1;
    int a = (i0 < NB) ? totals[i0] : 0;
    int b = (i1 < NB) ? totals[i1] : 0;
    s[tid] = a + b;
    __syncthreads();
    #pragma unroll
    for (int off = 1; off < 1024; off <<= 1) {
        int t = (tid >= off) ? s[tid - off] : 0;
        __syncthreads();
        s[tid] += t;
        __syncthreads();
    }
    int excl = s[tid] - (a + b);
    if (i0 < NB) bucketStart[i0] = excl;
    if (i1 < NB) bucketStart[i1] = excl + a;
    if (tid == 0) bucketStart[NB] = NE;
}

__global__ __launch_bounds__(256) void k_scatter(const int* __restrict__ src,
                                                 const int* __restrict__ dst,
                                                 const int* __restrict__ hist,
                                                 const int* __restrict__ bucketStart,
                                                 int* __restrict__ packed) {
    __shared__ int cur[NB];
    for (int b = threadIdx.x; b < NB; b += 256)
        cur[b] = hist[blockIdx.x * NB + b] + bucketStart[b];   // addback folded in
    __syncthreads();
    int base = blockIdx.x * CHUNK;
    for (int i = base + threadIdx.x; i < base + CHUNK; i += 256) {
        int d = dst[i];
        int pos = atomicAdd(&cur[d >> 6], 1);
        packed[pos] = src[i] | ((d & 63) << 17);   // src < 2^17, local node in [0,64)
    }
}

// per-bucket sort -> PADDED CSR (mult-of-4 rows, sentinel NN) + rowSE + dinv;
// then scale g1 rows of this bucket in-place by dinv.
// Padded bucket base: align4(bucketStart[b] + 200*b) — capacity >= total+197 >= padded.
__global__ __launch_bounds__(256) void k_bsort(const int* __restrict__ packed,
                                               const int* __restrict__ bucketStart,
                                               int* __restrict__ csr,
                                               int2* __restrict__ rowSE,
                                               float* __restrict__ dinv,
                                               __half2* __restrict__ g1) {
    __shared__ int cnt[CB];
    __shared__ int rsp[CB];    // inclusive prefix of padded counts
    __shared__ int cur[CB];
    __shared__ float dvs[CB];
    int b = blockIdx.x;
    if (threadIdx.x < CB) cnt[threadIdx.x] = 0;
    __syncthreads();
    int s0 = bucketStart[b], s1 = bucketStart[b + 1];
    for (int i = s0 + threadIdx.x; i < s1; i += 256)
        atomicAdd(&cnt[(packed[i] >> 17) & 63], 1);
    __syncthreads();
    int c = 0, cp = 0;
    if (threadIdx.x < CB) {
        c = cnt[threadIdx.x];
        cp = (c + 3) & ~3;
        rsp[threadIdx.x] = cp;
    }
    __syncthreads();
    #pragma unroll
    for (int off = 1; off < CB; off <<= 1) {
        int t = 0;
        if (threadIdx.x < CB && threadIdx.x >= off) t = rsp[threadIdx.x - off];
        __syncthreads();
        if (threadIdx.x < CB) rsp[threadIdx.x] += t;
        __syncthreads();
    }
    int base = (s0 + 200 * b + 3) & ~3;
    if (threadIdx.x < CB) {
        int start = base + rsp[threadIdx.x] - cp;      // exclusive padded prefix
        cur[threadIdx.x] = start;
        float dv = rsqrtf((float)(c + 1));
        dvs[threadIdx.x] = dv;
        int node = b * CB + threadIdx.x;
        if (node < NN) {
            rowSE[node] = make_int2(start, start + cp);
            dinv[node] = dv;
        }
    }
    __syncthreads();
    for (int i = s0 + threadIdx.x; i < s1; i += 256) {
        int pk = packed[i];
        int pos = atomicAdd(&cur[(pk >> 17) & 63], 1);
        csr[pos] = pk & 131071;
    }
    __syncthreads();
    if (threadIdx.x < CB) {
        int end = cur[threadIdx.x];                    // = start + c
        int endp = end + (cp - c);
        for (int p = end; p < endp; ++p) csr[p] = NN;  // sentinel -> zero row
    }
    // ---- scale g1 rows of this bucket: half2 range [b*512, b*512+512) ----
    int gbase = b * (CB * 8);
    #pragma unroll
    for (int r = 0; r < 2; ++r) {
        int i = r * 256 + threadIdx.x;
        int gi = gbase + i;
        if (gi < NN * 8) {
            float dv = dvs[i >> 3];
            float2 f = __half22float2(g1[gi]);
            g1[gi] = __floats2half2_rn(f.x * dv, f.y * dv);
        }
    }
}

// agg layer 1: 8 threads/node, branch-free padded loop, 4 gathers in flight.
// g1 pre-scaled: g2 = f16(relu(dv*(g1_d + sum_s g1_s) + b1) * dv)
__global__ __launch_bounds__(256) void k_agg1(const int* __restrict__ csr,
                                              const int2* __restrict__ rowSE,
                                              const __half2* __restrict__ g1,
                                              const float* __restrict__ dinv,
                                              const float* __restrict__ b1,
                                              __half2* __restrict__ g2) {
    if (blockIdx.x == 0 && threadIdx.x < 8)
        g2[NN * 8 + threadIdx.x] = __floats2half2_rn(0.f, 0.f);   // zero sentinel row
    int gid = blockIdx.x * 256 + threadIdx.x;
    int node = gid >> 3, c = gid & 7;
    if (node >= NN) return;
    int2 se = rowSE[node];
    float2 acc = __half22float2(g1[node * 8 + c]);   // self-loop term
    for (int e = se.x; e < se.y; e += 4) {
        int4 i4 = *(const int4*)(csr + e);
        float2 f0 = __half22float2(g1[i4.x * 8 + c]);
        float2 f1 = __half22float2(g1[i4.y * 8 + c]);
        float2 f2 = __half22float2(g1[i4.z * 8 + c]);
        float2 f3 = __half22float2(g1[i4.w * 8 + c]);
        acc.x += (f0.x + f1.x) + (f2.x + f3.x);
        acc.y += (f0.y + f1.y) + (f2.y + f3.y);
    }
    float dv = dinv[node];
    float2 bb = *(const float2*)(b1 + 2 * c);
    g2[node * 8 + c] = __floats2half2_rn(fmaxf(dv * acc.x + bb.x, 0.f) * dv,
                                         fmaxf(dv * acc.y + bb.y, 0.f) * dv);
}

// agg layer 2: same shape; p2 = f16(dv*(g2_d + sum_s g2_s))
__global__ __launch_bounds__(256) void k_agg2(const int* __restrict__ csr,
                                              const int2* __restrict__ rowSE,
                                              const __half2* __restrict__ g2,
                                              const float* __restrict__ dinv,
                                              __half2* __restrict__ p2h) {
    int gid = blockIdx.x * 256 + threadIdx.x;
    int node = gid >> 3, c = gid & 7;
    if (node >= NN) return;
    int2 se = rowSE[node];
    float2 acc = __half22float2(g2[node * 8 + c]);   // self-loop term
    for (int e = se.x; e < se.y; e += 4) {
        int4 i4 = *(const int4*)(csr + e);
        float2 f0 = __half22float2(g2[i4.x * 8 + c]);
        float2 f1 = __half22float2(g2[i4.y * 8 + c]);
        float2 f2 = __half22float2(g2[i4.z * 8 + c]);
        float2 f3 = __half22float2(g2[i4.w * 8 + c]);
        acc.x += (f0.x + f1.x) + (f2.x + f3.x);
        acc.y += (f0.y + f1.y) + (f2.y + f3.y);
    }
    float dv = dinv[node];
    p2h[node * 8 + c] = __floats2half2_rn(dv * acc.x, dv * acc.y);
}

// out = p2 @ W2 + b2; 32 nodes/block, thread = 4 nodes x 4 feats (f16 p2 input)
__global__ __launch_bounds__(256) void k_gemm2(const __half2* __restrict__ p2h,
                                               const float* __restrict__ W2,
                                               const float* __restrict__ b2,
                                               float* __restrict__ out) {
    __shared__ __align__(16) float w[FH * FI];
    __shared__ float pst[FH][33];                     // +1 pad: conflict-free
    float4* w4s = (float4*)w;
    w4s[threadIdx.x] = ((const float4*)W2)[threadIdx.x];
    w4s[threadIdx.x + 256] = ((const float4*)W2)[threadIdx.x + 256];
    int base = blockIdx.x * 32;
    {
        int n = threadIdx.x >> 3, cc = threadIdx.x & 7;
        int gn = base + n;
        __half2 hv = (gn < NN) ? p2h[gn * 8 + cc] : __floats2half2_rn(0.f, 0.f);
        float2 f = __half22float2(hv);
        pst[2 * cc][n]     = f.x;
        pst[2 * cc + 1][n] = f.y;
    }
    __syncthreads();
    int fg = threadIdx.x & 31;    // feature quad
    int ng = threadIdx.x >> 5;    // node group
    float4 bb = ((const float4*)b2)[fg];
    float a2[4][4];
    #pragma unroll
    for (int i = 0; i < 4; ++i) {
        a2[i][0] = bb.x; a2[i][1] = bb.y; a2[i][2] = bb.z; a2[i][3] = bb.w;
    }
    #pragma unroll
    for (int k = 0; k < FH; ++k) {
        float4 wv = w4s[k * 32 + fg];
        #pragma unroll
        for (int i = 0; i < 4; ++i) {
            float xv = pst[k][ng * 4 + i];
            a2[i][0] += xv * wv.x; a2[i][1] += xv * wv.y;
            a2[i][2] += xv * wv.z; a2[i][3] += xv * wv.w;
        }
    }
    #pragma unroll
    for (int i = 0; i < 4; ++i) {
        int gn = base + ng * 4 + i;
        if (gn < NN)
            ((float4*)out)[gn * 32 + fg] =
                make_float4(a2[i][0], a2[i][1], a2[i][2], a2[i][3]);
    }
}

extern "C" void kernel_launch(void* const* d_in, const int* in_sizes, int n_in,
                              void* d_out, int out_size, void* d_ws, size_t ws_size,
                              hipStream_t stream) {
    const float* x  = (const float*)d_in[0];
    const int*   ei = (const int*)d_in[1];
    const float* W1 = (const float*)d_in[2];
    const float* b1 = (const float*)d_in[3];
    const float* W2 = (const float*)d_in[4];
    const float* b2 = (const float*)d_in[5];
    float* out = (float*)d_out;

    const int* src = ei;
    const int* dst = ei + NE;

    // workspace layout (~18.5 MB, 4-B units).
    // csrPad = NE + 200*NB (padded buckets); hist overlays csrPad (dead by bsort);
    // g2 + p2h overlay packed (dead after bsort).
    int2*  rowSE       = (int2*)d_ws;                 // [NN]        off 0 (8B aligned)
    float* dinv        = (float*)(rowSE + NN);        // [NN]        off 200,000
    int*   totals      = (int*)(dinv + NN);           // [NB]        off 300,000
    int*   bucketStart = totals + NB;                 // [NB+1]      off 301,563
    int*   csrPad      = bucketStart + NB + 1 + 1;    // [1,912,600] off 303,128 (16B aligned)
    int*   hist        = csrPad;                      // [GC*NB]=800,256 overlay
    int*   packed      = csrPad + (NE + 200 * NB);    // [NE+16]     off 2,215,728 (16B aligned)
    __half2* g2        = (__half2*)packed;            // [(NN+1)*8] overlay
    __half2* p2h       = g2 + (NN + 1) * 8;           // [NN*8]     overlay
    __half2* g1        = (__half2*)(packed + NE + 16);// [(NN+1)*8]

    k_count_gemm1 <<<GC + (NN + 255) / 256, 256, 0, stream>>>(dst, hist, x, W1, g1);
    k_scan_chunks <<<(NB + SCB - 1) / SCB, 256, 0, stream>>>(hist, totals);
    k_scan_buckets<<<1, 1024, 0, stream>>>(totals, bucketStart, g1);
    k_scatter     <<<GC, 256, 0, stream>>>(src, dst, hist, bucketStart, packed);
    k_bsort       <<<NB, 256, 0, stream>>>(packed, bucketStart, csrPad, rowSE, dinv, g1);
    k_agg1        <<<(NN * 8) / 256, 256, 0, stream>>>(csrPad, rowSE, g1, dinv, b1, g2);
    k_agg2        <<<(NN * 8) / 256, 256, 0, stream>>>(csrPad, rowSE, g2, dinv, p2h);
    k_gemm2       <<<(NN + 31) / 32, 256, 0, stream>>>(p2h, W2, b2, out);
}